// Round 3
// baseline (3729.362 us; speedup 1.0000x reference)
//
#include <hip/hip_runtime.h>

typedef unsigned short u16;
typedef __bf16 bf16_t;
typedef __attribute__((ext_vector_type(8))) __bf16 bf16x8;
typedef __attribute__((ext_vector_type(4))) float f32x4;

#define NPTS 65536
#define NCHUNK 4
#define NC (NPTS / NCHUNK)

__device__ __forceinline__ u16 f2b(float f) {
    unsigned u = __float_as_uint(f);
    unsigned r = 0x7fffu + ((u >> 16) & 1u);  // RNE
    u += r;
    return (u16)(u >> 16);
}

__device__ __forceinline__ float b2f(u16 u) {
    union { float f; unsigned i; } v;
    v.i = ((unsigned)u) << 16;
    return v.f;
}

// exact 2-term split: v = hi + lo to ~2^-17 relative
__device__ __forceinline__ void split2(float v, u16& h, u16& l) {
    h = f2b(v);
    l = f2b(v - b2f(h));
}

__device__ __forceinline__ void async_copy16(const u16* g, u16* l) {
    __builtin_amdgcn_global_load_lds(
        (const __attribute__((address_space(1))) void*)g,
        (__attribute__((address_space(3))) void*)l, 16, 0, 0);
}

// ---------------- KNN + xyz_aug assembly (hi/lo planes, stride 32) ----------------
__global__ __launch_bounds__(256) void knn_kernel(const float* __restrict__ cxyz,
                                                  u16* __restrict__ augH,
                                                  u16* __restrict__ augL) {
#pragma clang fp contract(off)
    const int lane = threadIdx.x & 63;
    const int wave = threadIdx.x >> 6;
    const size_t p = (size_t)blockIdx.x * 4 + wave;
    const float* row = cxyz + p * 1539;
    u16* oh = augH + p * 32;
    u16* ol = augL + p * 32;

    float vals[24];
    const float* lp = row + 3 + lane * 24;
#pragma unroll
    for (int i = 0; i < 24; ++i) vals[i] = lp[i];

    float x0 = row[0], y0 = row[1], z0 = row[2];

    unsigned long long cand[8];
#pragma unroll
    for (int t = 0; t < 8; ++t) {
        float dx = x0 - vals[3 * t + 0];
        float dy = y0 - vals[3 * t + 1];
        float dz = z0 - vals[3 * t + 2];
        float d2 = dx * dx + dy * dy;   // contract off: matches np eval order
        d2 = d2 + dz * dz;
        cand[t] = (((unsigned long long)__float_as_uint(d2)) << 32) |
                  (unsigned)(lane * 8 + t);
    }

    for (int r = 0; r < 8; ++r) {
        unsigned long long m = cand[0];
#pragma unroll
        for (int t = 1; t < 8; ++t) m = (cand[t] < m) ? cand[t] : m;
#pragma unroll
        for (int o = 1; o < 64; o <<= 1) {
            unsigned long long o2 = __shfl_xor(m, o, 64);
            m = (o2 < m) ? o2 : m;
        }
#pragma unroll
        for (int t = 0; t < 8; ++t)
            if (cand[t] == m) cand[t] = ~0ULL;
        if (lane == r) {
            unsigned jw = (unsigned)m;
#pragma unroll
            for (int c = 0; c < 3; ++c) {
                u16 h, l;
                split2(row[3 + 3 * jw + c], h, l);
                oh[3 + 3 * r + c] = h;
                ol[3 + 3 * r + c] = l;
            }
        }
    }

    if (lane < 3) {
        u16 h, l;
        split2(row[lane], h, l);
        oh[lane] = h;
        ol[lane] = l;
    }
    if (lane >= 27 && lane < 32) { oh[lane] = 0; ol[lane] = 0; }
}

// ---------------- weight packing (fp32 -> hi/lo bf16, transpose + K-pad) ----------------
__global__ __launch_bounds__(256) void prep_w1(const float* __restrict__ Wf,
                                               u16* __restrict__ WH, u16* __restrict__ WL) {
    int idx = blockIdx.x * 256 + threadIdx.x;
    if (idx >= 512 * 1568) return;
    int n = idx / 1568, kp = idx % 1568;
    float v = 0.f;
    if (kp < 27) v = Wf[(size_t)kp * 512 + n];
    else if (kp >= 32) v = Wf[(size_t)(kp - 5) * 512 + n];
    u16 h, l; split2(v, h, l);
    WH[idx] = h; WL[idx] = l;
}

__global__ __launch_bounds__(256) void prep_win(const float* __restrict__ Win,
                                                u16* __restrict__ WH, u16* __restrict__ WL) {
    int idx = blockIdx.x * 256 + threadIdx.x;
    if (idx >= 3 * 512 * 2080) return;
    int b = idx / (512 * 2080);
    int r = idx % (512 * 2080);
    int n = r / 2080, kp = r % 2080;
    float v = 0.f;
    if (kp < 539) v = Win[((size_t)b * 2075 + kp) * 512 + n];
    else if (kp >= 544) v = Win[((size_t)b * 2075 + kp - 5) * 512 + n];
    u16 h, l; split2(v, h, l);
    WH[idx] = h; WL[idx] = l;
}

__global__ __launch_bounds__(256) void prep_wh(const float* __restrict__ Wh,
                                               u16* __restrict__ WH, u16* __restrict__ WL) {
    int idx = blockIdx.x * 256 + threadIdx.x;
    if (idx >= 8 * 512 * 512) return;
    int m = idx / (512 * 512);
    int r = idx % (512 * 512);
    int n = r / 512, k = r % 512;
    u16 h, l; split2(Wh[((size_t)m * 512 + k) * 512 + n], h, l);
    WH[idx] = h; WL[idx] = l;
}

// ---------------- split-precision GEMM: C = relu(A @ B^T + bias) ----------------
// Virtual A = [x (kt0 tiles, hi/lo bf16 ld 512) | aug (kt1 tiles, hi/lo ld 32) |
//              latent (kt2 tiles, fp32 ld 1539, split on the fly)]
// B = hi/lo bf16 planes, [512][ktot*32] k-contiguous.
// Each tile: acc += ah*bh + ah*bl + al*bh  (3 MFMAs -> ~fp32-faithful)
__global__ __launch_bounds__(256) void gemm_split(
    const u16* __restrict__ XH, const u16* __restrict__ XL, int kt0,
    const u16* __restrict__ GH, const u16* __restrict__ GL, int kt1,
    const float* __restrict__ LF, int kt2,
    const u16* __restrict__ BH, const u16* __restrict__ BL,
    const float* __restrict__ bias,
    u16* __restrict__ CH, u16* __restrict__ CL) {
    __shared__ u16 AsH[128 * 32];
    __shared__ u16 AsL[128 * 32];
    __shared__ u16 BsH[128 * 32];
    __shared__ u16 BsL[128 * 32];
    const int tid = threadIdx.x;
    const int lane = tid & 63;
    const int wave = tid >> 6;
    const int e0 = kt0, e1 = kt0 + kt1, ktot = kt0 + kt1 + kt2;
    const size_t ldB = (size_t)ktot * 32;
    const size_t mbase = (size_t)blockIdx.x * 128;
    const int nbase = blockIdx.y * 128;

    f32x4 acc[4][4];
#pragma unroll
    for (int i = 0; i < 4; ++i)
#pragma unroll
        for (int j = 0; j < 4; ++j) acc[i][j] = (f32x4){0.f, 0.f, 0.f, 0.f};

    const int r4 = lane >> 2;         // 0..15
    const int c8 = (lane & 3) * 8;    // 0/8/16/24
    u16* lAH0 = &AsH[(wave * 32 + 0) * 32];
    u16* lAH1 = &AsH[(wave * 32 + 16) * 32];
    u16* lAL0 = &AsL[(wave * 32 + 0) * 32];
    u16* lAL1 = &AsL[(wave * 32 + 16) * 32];
    u16* lBH0 = &BsH[(wave * 32 + 0) * 32];
    u16* lBH1 = &BsH[(wave * 32 + 16) * 32];
    u16* lBL0 = &BsL[(wave * 32 + 0) * 32];
    u16* lBL1 = &BsL[(wave * 32 + 16) * 32];
    const size_t arow0 = mbase + wave * 32 + r4;
    const size_t brow0 = (size_t)nbase + wave * 32 + r4;

    const int m0 = (wave & 1) * 64;
    const int n0 = (wave >> 1) * 64;
    const int rowsel = lane & 15;
    const int quad8 = (lane >> 4) * 8;

    for (int t = 0; t < ktot; ++t) {
        if (t < e0) {
            const size_t off = arow0 * 512 + t * 32 + c8;
            async_copy16(XH + off, lAH0);
            async_copy16(XH + off + 16 * 512, lAH1);
            async_copy16(XL + off, lAL0);
            async_copy16(XL + off + 16 * 512, lAL1);
        } else if (t < e1) {
            const size_t off = arow0 * 32 + (t - e0) * 32 + c8;
            async_copy16(GH + off, lAH0);
            async_copy16(GH + off + 16 * 32, lAH1);
            async_copy16(GL + off, lAL0);
            async_copy16(GL + off + 16 * 32, lAL1);
        } else {
            // fp32 latent: load + exact split + LDS store
            const int kf = (t - e1) * 32 + c8;
            const float* g0 = LF + arow0 * (size_t)1539 + kf;
            const float* g1 = g0 + (size_t)16 * 1539;
            unsigned h0[4], l0[4], h1[4], l1[4];
#pragma unroll
            for (int i = 0; i < 4; ++i) {
                u16 ha, la, hb, lb;
                split2(g0[2 * i], ha, la);
                split2(g0[2 * i + 1], hb, lb);
                h0[i] = (unsigned)ha | ((unsigned)hb << 16);
                l0[i] = (unsigned)la | ((unsigned)lb << 16);
                split2(g1[2 * i], ha, la);
                split2(g1[2 * i + 1], hb, lb);
                h1[i] = (unsigned)ha | ((unsigned)hb << 16);
                l1[i] = (unsigned)la | ((unsigned)lb << 16);
            }
            *(uint4*)&AsH[(wave * 32 + r4) * 32 + c8] = make_uint4(h0[0], h0[1], h0[2], h0[3]);
            *(uint4*)&AsL[(wave * 32 + r4) * 32 + c8] = make_uint4(l0[0], l0[1], l0[2], l0[3]);
            *(uint4*)&AsH[(wave * 32 + 16 + r4) * 32 + c8] = make_uint4(h1[0], h1[1], h1[2], h1[3]);
            *(uint4*)&AsL[(wave * 32 + 16 + r4) * 32 + c8] = make_uint4(l1[0], l1[1], l1[2], l1[3]);
        }
        {
            const size_t off = brow0 * ldB + t * 32 + c8;
            async_copy16(BH + off, lBH0);
            async_copy16(BH + off + 16 * ldB, lBH1);
            async_copy16(BL + off, lBL0);
            async_copy16(BL + off + 16 * ldB, lBL1);
        }
        __syncthreads();

        bf16x8 ah[4], al[4], bh[4], bl[4];
#pragma unroll
        for (int i = 0; i < 4; ++i) {
            const int ra = (m0 + i * 16 + rowsel) * 32 + quad8;
            ah[i] = __builtin_bit_cast(bf16x8, *(const uint4*)&AsH[ra]);
            al[i] = __builtin_bit_cast(bf16x8, *(const uint4*)&AsL[ra]);
            const int rb = (n0 + i * 16 + rowsel) * 32 + quad8;
            bh[i] = __builtin_bit_cast(bf16x8, *(const uint4*)&BsH[rb]);
            bl[i] = __builtin_bit_cast(bf16x8, *(const uint4*)&BsL[rb]);
        }
#pragma unroll
        for (int i = 0; i < 4; ++i)
#pragma unroll
            for (int j = 0; j < 4; ++j)
                acc[i][j] = __builtin_amdgcn_mfma_f32_16x16x32_bf16(ah[i], bh[j], acc[i][j], 0, 0, 0);
#pragma unroll
        for (int i = 0; i < 4; ++i)
#pragma unroll
            for (int j = 0; j < 4; ++j)
                acc[i][j] = __builtin_amdgcn_mfma_f32_16x16x32_bf16(ah[i], bl[j], acc[i][j], 0, 0, 0);
#pragma unroll
        for (int i = 0; i < 4; ++i)
#pragma unroll
            for (int j = 0; j < 4; ++j)
                acc[i][j] = __builtin_amdgcn_mfma_f32_16x16x32_bf16(al[i], bh[j], acc[i][j], 0, 0, 0);
        __syncthreads();
    }

    // epilogue: bias + relu, exact hi/lo split store. D: col=lane&15, row=(lane>>4)*4+reg
#pragma unroll
    for (int j = 0; j < 4; ++j) {
        const int col = nbase + n0 + j * 16 + (lane & 15);
        const float bv = bias[col];
#pragma unroll
        for (int i = 0; i < 4; ++i) {
#pragma unroll
            for (int r = 0; r < 4; ++r) {
                const size_t rowg = mbase + m0 + i * 16 + (lane >> 4) * 4 + r;
                float v = acc[i][j][r] + bv;
                v = v > 0.f ? v : 0.f;
                u16 h, l;
                split2(v, h, l);
                CH[rowg * 512 + col] = h;
                CL[rowg * 512 + col] = l;
            }
        }
    }
}

// ---------------- final 512 -> 1 + tanh (fp32 out) ----------------
__global__ __launch_bounds__(256) void out_kernel(const u16* __restrict__ xH,
                                                  const u16* __restrict__ xL,
                                                  const float* __restrict__ Wout,
                                                  const float* __restrict__ bout,
                                                  float* __restrict__ out) {
    const int lane = threadIdx.x & 63;
    const int wave = threadIdx.x >> 6;
    const size_t p = (size_t)blockIdx.x * 4 + wave;
    uint4 hv = *(const uint4*)(xH + p * 512 + lane * 8);
    uint4 lv = *(const uint4*)(xL + p * 512 + lane * 8);
    const u16* hs = (const u16*)&hv;
    const u16* ls = (const u16*)&lv;
    float s = 0.f;
#pragma unroll
    for (int i = 0; i < 8; ++i) {
        float v = b2f(hs[i]) + b2f(ls[i]);
        s += v * Wout[lane * 8 + i];
    }
#pragma unroll
    for (int o = 1; o < 64; o <<= 1) s += __shfl_xor(s, o, 64);
    if (lane == 0) out[p] = tanhf(s + bout[0]);
}

extern "C" void kernel_launch(void* const* d_in, const int* in_sizes, int n_in,
                              void* d_out, int out_size, void* d_ws, size_t ws_size,
                              hipStream_t stream) {
    const float* cxyz = (const float*)d_in[0];
    const float* Wf   = (const float*)d_in[1];
    const float* bf   = (const float*)d_in[2];
    const float* Win  = (const float*)d_in[3];
    const float* bin  = (const float*)d_in[4];
    const float* Wh   = (const float*)d_in[5];
    const float* bh   = (const float*)d_in[6];
    const float* Wout = (const float*)d_in[7];
    const float* bout = (const float*)d_in[8];
    float* out = (float*)d_out;
    u16* wsb = (u16*)d_ws;

    const size_t N = NPTS;
    // ws layout (u16 elems), total ~100 MB
    u16* augH = wsb;                                   // N*32
    u16* augL = augH + N * 32;                         // N*32
    u16* xaH  = augL + N * 32;                         // NC*512
    u16* xaL  = xaH + (size_t)NC * 512;
    u16* xbH  = xaL + (size_t)NC * 512;
    u16* xbL  = xbH + (size_t)NC * 512;
    u16* W1pH = xbL + (size_t)NC * 512;                // 512*1568
    u16* W1pL = W1pH + (size_t)512 * 1568;
    u16* WinpH = W1pL + (size_t)512 * 1568;            // 3*512*2080
    u16* WinpL = WinpH + (size_t)3 * 512 * 2080;
    u16* WhpH = WinpL + (size_t)3 * 512 * 2080;        // 8*512*512
    u16* WhpL = WhpH + (size_t)8 * 512 * 512;

    // 1. KNN + aug assembly (all N)
    knn_kernel<<<dim3(N / 4), dim3(256), 0, stream>>>(cxyz, augH, augL);

    // 2. weight packing
    prep_w1<<<dim3((512 * 1568 + 255) / 256), dim3(256), 0, stream>>>(Wf, W1pH, W1pL);
    prep_win<<<dim3((3 * 512 * 2080 + 255) / 256), dim3(256), 0, stream>>>(Win, WinpH, WinpL);
    prep_wh<<<dim3((8 * 512 * 512 + 255) / 256), dim3(256), 0, stream>>>(Wh, WhpH, WhpL);

    const dim3 gg(NC / 128, 4), gb(256);
    const size_t WH = (size_t)512 * 512;
    const size_t WI = (size_t)512 * 2080;

    for (int c = 0; c < NCHUNK; ++c) {
        const size_t cb = (size_t)c * NC;
        const float* LF = cxyz + cb * 1539 + 3;
        const u16* gH = augH + cb * 32;
        const u16* gL = augL + cb * 32;

        u16 *curH = xaH, *curL = xaL, *nxtH = xbH, *nxtL = xbL;

        // first layer: K = 32(aug) + 1536(latent)
        gemm_split<<<gg, gb, 0, stream>>>(nullptr, nullptr, 0, gH, gL, 1, LF, 48,
                                          W1pH, W1pL, bf, curH, curL);
        // block 0 hidden
        gemm_split<<<gg, gb, 0, stream>>>(curH, curL, 16, nullptr, nullptr, 0, nullptr, 0,
                                          WhpH + 0 * WH, WhpL + 0 * WH, bh + 0 * 512, nxtH, nxtL);
        { u16* t; t = curH; curH = nxtH; nxtH = t; t = curL; curL = nxtL; nxtL = t; }
        gemm_split<<<gg, gb, 0, stream>>>(curH, curL, 16, nullptr, nullptr, 0, nullptr, 0,
                                          WhpH + 1 * WH, WhpL + 1 * WH, bh + 1 * 512, nxtH, nxtL);
        { u16* t; t = curH; curH = nxtH; nxtH = t; t = curL; curL = nxtL; nxtL = t; }

        for (int b = 1; b < 4; ++b) {
            gemm_split<<<gg, gb, 0, stream>>>(curH, curL, 16, gH, gL, 1, LF, 48,
                                              WinpH + (b - 1) * WI, WinpL + (b - 1) * WI,
                                              bin + (b - 1) * 512, nxtH, nxtL);
            { u16* t; t = curH; curH = nxtH; nxtH = t; t = curL; curL = nxtL; nxtL = t; }
            gemm_split<<<gg, gb, 0, stream>>>(curH, curL, 16, nullptr, nullptr, 0, nullptr, 0,
                                              WhpH + (2 * b) * WH, WhpL + (2 * b) * WH,
                                              bh + (2 * b) * 512, nxtH, nxtL);
            { u16* t; t = curH; curH = nxtH; nxtH = t; t = curL; curL = nxtL; nxtL = t; }
            gemm_split<<<gg, gb, 0, stream>>>(curH, curL, 16, nullptr, nullptr, 0, nullptr, 0,
                                              WhpH + (2 * b + 1) * WH, WhpL + (2 * b + 1) * WH,
                                              bh + (2 * b + 1) * 512, nxtH, nxtL);
            { u16* t; t = curH; curH = nxtH; nxtH = t; t = curL; curL = nxtL; nxtL = t; }
        }

        out_kernel<<<dim3(NC / 4), dim3(256), 0, stream>>>(curH, curL, Wout, bout, out + cb);
    }
}

// Round 4
// 2168.568 us; speedup vs baseline: 1.7197x; 1.7197x over previous
//
#include <hip/hip_runtime.h>

typedef unsigned short u16;
typedef _Float16 f16;
typedef __attribute__((ext_vector_type(8))) _Float16 f16x8;
typedef __attribute__((ext_vector_type(4))) float f32x4;

#define NPTS 65536

__device__ __forceinline__ u16 f2h(float f) {
    f16 h = (f16)f;  // v_cvt_f16_f32, RNE
    return __builtin_bit_cast(u16, h);
}

__device__ __forceinline__ unsigned pack2(float a, float b) {
    return (unsigned)f2h(a) | ((unsigned)f2h(b) << 16);
}

__device__ __forceinline__ void async_copy16(const u16* g, u16* l) {
    __builtin_amdgcn_global_load_lds(
        (const __attribute__((address_space(1))) void*)g,
        (__attribute__((address_space(3))) void*)l, 16, 0, 0);
}

// ---------------- KNN + full x_ assembly (f16, stride 1568) ----------------
// xpad row: [xyz(3) | sel(24) | zeros(5) | latent(1536)]   (one wave per point)
__global__ __launch_bounds__(256) void knn_kernel(const float* __restrict__ cxyz,
                                                  u16* __restrict__ xpad) {
#pragma clang fp contract(off)
    const int lane = threadIdx.x & 63;
    const int wave = threadIdx.x >> 6;
    const size_t p = (size_t)blockIdx.x * 4 + wave;
    const float* row = cxyz + p * 1539;
    u16* orow = xpad + p * 1568;

    float vals[24];
    const float* lp = row + 3 + lane * 24;
#pragma unroll
    for (int i = 0; i < 24; ++i) vals[i] = lp[i];

    float x0 = row[0], y0 = row[1], z0 = row[2];

    unsigned long long cand[8];
#pragma unroll
    for (int t = 0; t < 8; ++t) {
        float dx = x0 - vals[3 * t + 0];
        float dy = y0 - vals[3 * t + 1];
        float dz = z0 - vals[3 * t + 2];
        float d2 = dx * dx + dy * dy;   // contract off: matches np eval order
        d2 = d2 + dz * dz;
        cand[t] = (((unsigned long long)__float_as_uint(d2)) << 32) |
                  (unsigned)(lane * 8 + t);
    }

    for (int r = 0; r < 8; ++r) {
        unsigned long long m = cand[0];
#pragma unroll
        for (int t = 1; t < 8; ++t) m = (cand[t] < m) ? cand[t] : m;
#pragma unroll
        for (int o = 1; o < 64; o <<= 1) {
            unsigned long long o2 = __shfl_xor(m, o, 64);
            m = (o2 < m) ? o2 : m;
        }
#pragma unroll
        for (int t = 0; t < 8; ++t)
            if (cand[t] == m) cand[t] = ~0ULL;
        if (lane == r) {
            unsigned jw = (unsigned)m;
            orow[3 + 3 * r + 0] = f2h(row[3 + 3 * jw + 0]);
            orow[3 + 3 * r + 1] = f2h(row[3 + 3 * jw + 1]);
            orow[3 + 3 * r + 2] = f2h(row[3 + 3 * jw + 2]);
        }
    }

    if (lane < 3) orow[lane] = f2h(row[lane]);
    if (lane >= 27 && lane < 32) orow[lane] = 0;

    // latent: 24 f16 per lane, 16B-aligned vector stores (64 + 48*lane bytes)
    unsigned w[12];
#pragma unroll
    for (int i = 0; i < 12; ++i) w[i] = pack2(vals[2 * i], vals[2 * i + 1]);
    uint4* op = (uint4*)(orow + 32 + lane * 24);
    op[0] = make_uint4(w[0], w[1], w[2], w[3]);
    op[1] = make_uint4(w[4], w[5], w[6], w[7]);
    op[2] = make_uint4(w[8], w[9], w[10], w[11]);
}

// ---------------- weight packing (fp32 -> f16, transpose + K-pad) ----------------
__global__ __launch_bounds__(256) void prep_w1(const float* __restrict__ Wf,
                                               u16* __restrict__ W1p) {
    int idx = blockIdx.x * 256 + threadIdx.x;
    if (idx >= 512 * 1568) return;
    int n = idx / 1568, kp = idx % 1568;
    float v = 0.f;
    if (kp < 27) v = Wf[(size_t)kp * 512 + n];
    else if (kp >= 32) v = Wf[(size_t)(kp - 5) * 512 + n];
    W1p[idx] = f2h(v);
}

__global__ __launch_bounds__(256) void prep_win(const float* __restrict__ Win,
                                                u16* __restrict__ Winp) {
    int idx = blockIdx.x * 256 + threadIdx.x;
    if (idx >= 3 * 512 * 2080) return;
    int b = idx / (512 * 2080);
    int r = idx % (512 * 2080);
    int n = r / 2080, kp = r % 2080;
    float v = 0.f;
    if (kp < 539) v = Win[((size_t)b * 2075 + kp) * 512 + n];
    else if (kp >= 544) v = Win[((size_t)b * 2075 + kp - 5) * 512 + n];
    Winp[idx] = f2h(v);
}

__global__ __launch_bounds__(256) void prep_wh(const float* __restrict__ Wh,
                                               u16* __restrict__ Whp) {
    int idx = blockIdx.x * 256 + threadIdx.x;
    if (idx >= 8 * 512 * 512) return;
    int m = idx / (512 * 512);
    int r = idx % (512 * 512);
    int n = r / 512, k = r % 512;
    Whp[idx] = f2h(Wh[((size_t)m * 512 + k) * 512 + n]);
}

// ---------------- f16 GEMM: C[M x 512] = relu(A @ B^T + bias) ----------------
// Virtual A = [seg0 (kt0 tiles, ld0) | seg1 (kt1 tiles, ld1)], both f16 k-contiguous.
// B packed transposed [512][K] f16, K = (kt0+kt1)*32. bias fp32. C f16.
__global__ __launch_bounds__(256) void gemm_f16(
    const u16* __restrict__ A0, int ld0, int kt0,
    const u16* __restrict__ A1, int ld1, int kt1,
    const u16* __restrict__ B,
    const float* __restrict__ bias,
    u16* __restrict__ C) {
    __shared__ u16 As[128 * 32];
    __shared__ u16 Bs[128 * 32];
    const int tid = threadIdx.x;
    const int lane = tid & 63;
    const int wave = tid >> 6;
    const int ktot = kt0 + kt1;
    const size_t ldB = (size_t)ktot * 32;
    const size_t mbase = (size_t)blockIdx.x * 128;
    const int nbase = blockIdx.y * 128;

    f32x4 acc[4][4];
#pragma unroll
    for (int i = 0; i < 4; ++i)
#pragma unroll
        for (int j = 0; j < 4; ++j) acc[i][j] = (f32x4){0.f, 0.f, 0.f, 0.f};

    const int r4 = lane >> 2;         // 0..15
    const int c8 = (lane & 3) * 8;    // 0/8/16/24
    u16* lA0 = &As[(wave * 32 + 0) * 32];
    u16* lA1 = &As[(wave * 32 + 16) * 32];
    u16* lB0 = &Bs[(wave * 32 + 0) * 32];
    u16* lB1 = &Bs[(wave * 32 + 16) * 32];
    const size_t arow0 = mbase + wave * 32 + r4;
    const size_t brow0 = (size_t)nbase + wave * 32 + r4;

    const int m0 = (wave & 1) * 64;
    const int n0 = (wave >> 1) * 64;
    const int rowsel = lane & 15;
    const int quad8 = (lane >> 4) * 8;

    for (int t = 0; t < ktot; ++t) {
        if (t < kt0) {
            const size_t off = arow0 * (size_t)ld0 + t * 32 + c8;
            async_copy16(A0 + off, lA0);
            async_copy16(A0 + off + 16 * (size_t)ld0, lA1);
        } else {
            const size_t off = arow0 * (size_t)ld1 + (t - kt0) * 32 + c8;
            async_copy16(A1 + off, lA0);
            async_copy16(A1 + off + 16 * (size_t)ld1, lA1);
        }
        {
            const size_t off = brow0 * ldB + t * 32 + c8;
            async_copy16(B + off, lB0);
            async_copy16(B + off + 16 * ldB, lB1);
        }
        __syncthreads();

        f16x8 af[4], bfr[4];
#pragma unroll
        for (int i = 0; i < 4; ++i) {
            af[i]  = __builtin_bit_cast(f16x8, *(const uint4*)&As[(m0 + i * 16 + rowsel) * 32 + quad8]);
            bfr[i] = __builtin_bit_cast(f16x8, *(const uint4*)&Bs[(n0 + i * 16 + rowsel) * 32 + quad8]);
        }
#pragma unroll
        for (int i = 0; i < 4; ++i)
#pragma unroll
            for (int j = 0; j < 4; ++j)
                acc[i][j] = __builtin_amdgcn_mfma_f32_16x16x32_f16(
                    af[i], bfr[j], acc[i][j], 0, 0, 0);
        __syncthreads();
    }

    // epilogue: bias + relu -> f16. D layout: col=lane&15, row=(lane>>4)*4+reg
#pragma unroll
    for (int j = 0; j < 4; ++j) {
        const int col = nbase + n0 + j * 16 + (lane & 15);
        const float bv = bias[col];
#pragma unroll
        for (int i = 0; i < 4; ++i) {
#pragma unroll
            for (int r = 0; r < 4; ++r) {
                const size_t rowg = mbase + m0 + i * 16 + (lane >> 4) * 4 + r;
                float v = acc[i][j][r] + bv;
                v = v > 0.f ? v : 0.f;
                C[rowg * 512 + col] = f2h(v);
            }
        }
    }
}

// ---------------- final 512 -> 1 + tanh (fp32 out) ----------------
__global__ __launch_bounds__(256) void out_kernel(const u16* __restrict__ x,
                                                  const float* __restrict__ Wout,
                                                  const float* __restrict__ bout,
                                                  float* __restrict__ out) {
    const int lane = threadIdx.x & 63;
    const int wave = threadIdx.x >> 6;
    const size_t p = (size_t)blockIdx.x * 4 + wave;
    uint4 xv = *(const uint4*)(x + p * 512 + lane * 8);
    const f16* xs = (const f16*)&xv;
    float s = 0.f;
#pragma unroll
    for (int i = 0; i < 8; ++i) s += (float)xs[i] * Wout[lane * 8 + i];
#pragma unroll
    for (int o = 1; o < 64; o <<= 1) s += __shfl_xor(s, o, 64);
    if (lane == 0) out[p] = tanhf(s + bout[0]);
}

extern "C" void kernel_launch(void* const* d_in, const int* in_sizes, int n_in,
                              void* d_out, int out_size, void* d_ws, size_t ws_size,
                              hipStream_t stream) {
    const float* cxyz = (const float*)d_in[0];
    const float* Wf   = (const float*)d_in[1];
    const float* bf   = (const float*)d_in[2];
    const float* Win  = (const float*)d_in[3];
    const float* bin  = (const float*)d_in[4];
    const float* Wh   = (const float*)d_in[5];
    const float* bh   = (const float*)d_in[6];
    const float* Wout = (const float*)d_in[7];
    const float* bout = (const float*)d_in[8];
    float* out = (float*)d_out;
    u16* wsb = (u16*)d_ws;

    const size_t N = NPTS;
    // ws layout (u16 elems), ~352 MB total (ws observed ~1.6 GB)
    u16* xpad = wsb;                                  // N*1568
    u16* xa   = xpad + N * 1568;                      // N*512
    u16* xb   = xa + N * 512;                         // N*512
    u16* W1p  = xb + N * 512;                         // 512*1568
    u16* Winp = W1p + (size_t)512 * 1568;             // 3*512*2080
    u16* Whp  = Winp + (size_t)3 * 512 * 2080;        // 8*512*512

    // 1. KNN + full x_ assembly (f16)
    knn_kernel<<<dim3(N / 4), dim3(256), 0, stream>>>(cxyz, xpad);

    // 2. weight packing
    prep_w1<<<dim3((512 * 1568 + 255) / 256), dim3(256), 0, stream>>>(Wf, W1p);
    prep_win<<<dim3((3 * 512 * 2080 + 255) / 256), dim3(256), 0, stream>>>(Win, Winp);
    prep_wh<<<dim3((8 * 512 * 512 + 255) / 256), dim3(256), 0, stream>>>(Wh, Whp);

    const dim3 gg(N / 128, 4), gb(256);
    const size_t WH = (size_t)512 * 512;
    const size_t WI = (size_t)512 * 2080;

    // 3. MLP (ping-pong xa/xb)
    gemm_f16<<<gg, gb, 0, stream>>>(xpad, 1568, 49, nullptr, 0, 0, W1p, bf, xa);
    gemm_f16<<<gg, gb, 0, stream>>>(xa, 512, 16, nullptr, 0, 0, Whp + 0 * WH, bh + 0 * 512, xb);
    gemm_f16<<<gg, gb, 0, stream>>>(xb, 512, 16, nullptr, 0, 0, Whp + 1 * WH, bh + 1 * 512, xa);

    gemm_f16<<<gg, gb, 0, stream>>>(xa, 512, 16, xpad, 1568, 49, Winp + 0 * WI, bin + 0 * 512, xb);
    gemm_f16<<<gg, gb, 0, stream>>>(xb, 512, 16, nullptr, 0, 0, Whp + 2 * WH, bh + 2 * 512, xa);
    gemm_f16<<<gg, gb, 0, stream>>>(xa, 512, 16, nullptr, 0, 0, Whp + 3 * WH, bh + 3 * 512, xb);

    gemm_f16<<<gg, gb, 0, stream>>>(xb, 512, 16, xpad, 1568, 49, Winp + 1 * WI, bin + 1 * 512, xa);
    gemm_f16<<<gg, gb, 0, stream>>>(xa, 512, 16, nullptr, 0, 0, Whp + 4 * WH, bh + 4 * 512, xb);
    gemm_f16<<<gg, gb, 0, stream>>>(xb, 512, 16, nullptr, 0, 0, Whp + 5 * WH, bh + 5 * 512, xa);

    gemm_f16<<<gg, gb, 0, stream>>>(xa, 512, 16, xpad, 1568, 49, Winp + 2 * WI, bin + 2 * 512, xb);
    gemm_f16<<<gg, gb, 0, stream>>>(xb, 512, 16, nullptr, 0, 0, Whp + 6 * WH, bh + 6 * 512, xa);
    gemm_f16<<<gg, gb, 0, stream>>>(xa, 512, 16, nullptr, 0, 0, Whp + 7 * WH, bh + 7 * 512, xb);

    // 4. output head
    out_kernel<<<dim3(N / 4), dim3(256), 0, stream>>>(xb, Wout, bout, out);
}